// Round 5
// baseline (3052.172 us; speedup 1.0000x reference)
//
#include <hip/hip_runtime.h>
#include <hip/hip_fp16.h>
#include <stdint.h>

typedef _Float16 f16x8 __attribute__((ext_vector_type(8)));
typedef _Float16 f16x4 __attribute__((ext_vector_type(4)));
typedef float    f32x4 __attribute__((ext_vector_type(4)));

static constexpr int NROWS = 32768;   // b*n
static constexpr int NCODE = 8192;
static constexpr int DDIM  = 512;
static constexpr int BM = 256, BN = 256, BK = 64;
static constexpr int NBM = NROWS / BM;    // 128
static constexpr int NBN = NCODE / BN;    // 32
static constexpr int NPART = NBN * 2;     // 64 partials per row

// out layout (floats): quantize [NROWS*DDIM] | embed_ind [NROWS] | dist [NROWS*NCODE]
static constexpr size_t OFF_IND  = (size_t)NROWS * DDIM;
static constexpr size_t OFF_DIST = OFF_IND + NROWS;

// ws layout (bytes)
static constexpr size_t WS_XH   = 0;
static constexpr size_t WS_XL   = WS_XH + (size_t)NROWS * DDIM * 2;
static constexpr size_t WS_EH   = WS_XL + (size_t)NROWS * DDIM * 2;
static constexpr size_t WS_EL   = WS_EH + (size_t)NCODE * DDIM * 2;
static constexpr size_t WS_X2   = WS_EL + (size_t)NCODE * DDIM * 2;
static constexpr size_t WS_E2   = WS_X2 + (size_t)NROWS * 4;
static constexpr size_t WS_PART = WS_E2 + (size_t)NCODE * 4;

__device__ inline void gload_lds16(const void* g, void* l) {
  __builtin_amdgcn_global_load_lds((const __attribute__((address_space(1))) void*)g,
                                   (__attribute__((address_space(3))) void*)l,
                                   16, 0, 0);
}

// ---------- prep: fp32 -> (f16 hi, f16 lo) split + fp64-accumulated norms ----------
__global__ __launch_bounds__(128)
void prep_kernel(const float* __restrict__ x, const float* __restrict__ e,
                 _Float16* __restrict__ xh, _Float16* __restrict__ xl,
                 _Float16* __restrict__ eh, _Float16* __restrict__ el,
                 float* __restrict__ x2, float* __restrict__ e2)
{
  int bid = blockIdx.x;
  const float* src; _Float16 *dh, *dl; float* nrm;
  if (bid < NROWS) {
    src = x + (size_t)bid * DDIM;
    dh = xh + (size_t)bid * DDIM;  dl = xl + (size_t)bid * DDIM;
    nrm = x2 + bid;
  } else {
    int r = bid - NROWS;
    src = e + (size_t)r * DDIM;
    dh = eh + (size_t)r * DDIM;    dl = el + (size_t)r * DDIM;
    nrm = e2 + r;
  }
  int t = threadIdx.x;
  float4 v = reinterpret_cast<const float4*>(src)[t];
  double s = (double)v.x*v.x + (double)v.y*v.y + (double)v.z*v.z + (double)v.w*v.w;
  f16x4 h, l;
  h.x = (_Float16)v.x; l.x = (_Float16)(v.x - (float)h.x);
  h.y = (_Float16)v.y; l.y = (_Float16)(v.y - (float)h.y);
  h.z = (_Float16)v.z; l.z = (_Float16)(v.z - (float)h.z);
  h.w = (_Float16)v.w; l.w = (_Float16)(v.w - (float)h.w);
  reinterpret_cast<f16x4*>(dh)[t] = h;
  reinterpret_cast<f16x4*>(dl)[t] = l;
  #pragma unroll
  for (int m = 1; m < 64; m <<= 1) s += __shfl_xor(s, m);
  __shared__ double sh[2];
  if ((t & 63) == 0) sh[t >> 6] = s;
  __syncthreads();
  if (t == 0) nrm[0] = (float)(sh[0] + sh[1]);
}

// ---------- main: 256x256 read-ahead-pipelined split-GEMM + dist epilogue + partial argmin ----------
__global__ __launch_bounds__(512, 1)
void dist_gemm_kernel(const _Float16* __restrict__ xh, const _Float16* __restrict__ xl,
                      const _Float16* __restrict__ eh, const _Float16* __restrict__ el,
                      const float* __restrict__ x2, const float* __restrict__ e2,
                      float* __restrict__ dist, float2* __restrict__ part)
{
  __shared__ _Float16 L[2][2][BM * BK];   // [buf][A=0/B=1][256*64] = 128 KiB

  const int tid  = threadIdx.x;
  const int wid  = tid >> 6;
  const int lane = tid & 63;
  const int qwr  = wid >> 1;      // 0..3 : 32-row band within each 128-row half
  const int qwc  = wid & 1;       // 0..1 : 64-col half within each 128-col half

  // Locality swizzle: each XCD owns a fixed 4-wide bn strip (2 MB B panel -> L2-resident);
  // all XCDs sweep bm in the same order so A panels are L3-shared within a short window.
  const int flat = blockIdx.x;
  const int xcd  = flat & 7;
  const int idx  = flat >> 3;          // 0..511
  const int bn   = xcd * 4 + (idx & 3);
  const int bm   = idx >> 2;           // 0..127
  const int R  = bm * BM;
  const int Cc = bn * BN;

  const int l3 = lane >> 3;
  const int l7 = lane & 7;
  const int srcslot = ((l7 ^ l3) << 4);   // pre-swizzled global 16B-slot (inverse of read swizzle)

  // half: 0=A.h0(rows 0-127)  1=B.h0  2=A.h1(rows 128-255)  3=B.h1   (2 gloads per wave each)
  auto STAGE_HALF = [&](int t, int nb, int half) {
    const int ab = half & 1;
    const int hh = half >> 1;
    const _Float16* base;
    size_t rowbase;
    if (ab == 0) { base = (t < 16) ? xh : xl;              rowbase = (size_t)R;  }
    else         { base = (t < 8 || t >= 16) ? eh : el;    rowbase = (size_t)Cc; }
    const int k0b = (t & 7) * (BK * 2);
    #pragma unroll
    for (int i = 0; i < 2; ++i) {
      const int rr = hh * 128 + wid * 16 + i * 8;
      gload_lds16((const char*)base + (rowbase + rr + l3) * (DDIM * 2) + k0b + srcslot,
                  &L[nb][ab][rr * BK]);
    }
  };

  const int l15   = lane & 15;
  const int kslot = (lane >> 4) << 4;     // 0,16,32,48 byte k-slot

  auto LDA = [&](f16x8 (&af)[2][2], int b, int mq) {
    #pragma unroll
    for (int m = 0; m < 2; ++m)
      #pragma unroll
      for (int ks = 0; ks < 2; ++ks) {
        const int row = mq * 128 + qwr * 32 + m * 16 + l15;
        const int kb  = (ks * 64 + kslot) ^ ((row & 7) << 4);
        af[m][ks] = *(const f16x8*)((const char*)&L[b][0][0] + row * 128 + kb);
      }
  };
  auto LDB = [&](f16x8 (&bf)[4][2], int b, int nq) {
    #pragma unroll
    for (int n = 0; n < 4; ++n)
      #pragma unroll
      for (int ks = 0; ks < 2; ++ks) {
        const int row = nq * 128 + qwc * 64 + n * 16 + l15;
        const int kb  = (ks * 64 + kslot) ^ ((row & 7) << 4);
        bf[n][ks] = *(const f16x8*)((const char*)&L[b][1][0] + row * 128 + kb);
      }
  };

  f32x4 acc[2][2][2][4] = {};   // [mq][nq][m][n]

  auto MM = [&](f32x4 (&ac)[2][4], f16x8 (&af)[2][2], f16x8 (&bf)[4][2]) {
    __builtin_amdgcn_s_setprio(1);
    #pragma unroll
    for (int m = 0; m < 2; ++m)
      #pragma unroll
      for (int n = 0; n < 4; ++n)
        #pragma unroll
        for (int ks = 0; ks < 2; ++ks)
          ac[m][n] = __builtin_amdgcn_mfma_f32_16x16x32_f16(af[m][ks], bf[n][ks], ac[m][n], 0, 0, 0);
    __builtin_amdgcn_s_setprio(0);
  };

  // One tile: reads are issued ONE PHASE AHEAD of their consuming MFMA, pre-barrier,
  // so they overlap other waves' MFMAs. Ledger (2 vmem ops per stage-half):
  //   p1 vmcnt(2) confirms h3(t)      -> bf1 read @p2 safe
  //   p3 vmcnt(2) confirms h0,h1(t+1) -> af0n/bf0n reads @p4 safe
  //   p4 vmcnt(2) confirms h2(t+1)    -> af1 read @p1(t+1) safe
  auto TILE = [&](int t, int b, f16x8 (&af0)[2][2], f16x8 (&bf0)[4][2],
                  f16x8 (&af0n)[2][2], f16x8 (&bf0n)[4][2]) {
    f16x8 af1[2][2], bf1[4][2];

    // ---- p1: MFMA (0,0) [af0,bf0 in regs]; read af1 (A.h1 = half2 of t) ----
    if (t < 23) { STAGE_HALF(t + 1, b ^ 1, 0);
                  LDA(af1, b, 1);
                  asm volatile("s_waitcnt vmcnt(2)" ::: "memory"); }
    else        { LDA(af1, b, 1);
                  asm volatile("s_waitcnt vmcnt(0)" ::: "memory"); }
    __builtin_amdgcn_s_barrier();
    MM(acc[0][0], af0, bf0);

    // ---- p2: MFMA (1,0); read bf1 (B.h1 = half3 of t) ----
    if (t < 23) STAGE_HALF(t + 1, b ^ 1, 1);
    LDB(bf1, b, 1);
    __builtin_amdgcn_s_barrier();
    MM(acc[1][0], af1, bf0);

    // ---- p3: MFMA (1,1); no reads ----
    if (t < 23) { STAGE_HALF(t + 1, b ^ 1, 2);
                  asm volatile("s_waitcnt vmcnt(2)" ::: "memory"); }
    __builtin_amdgcn_s_barrier();
    MM(acc[1][1], af1, bf1);

    // ---- p4: MFMA (0,1); read next tile's (af0,bf0) from buf^1 ----
    if (t < 23) { STAGE_HALF(t + 1, b ^ 1, 3);
                  LDA(af0n, b ^ 1, 0);
                  LDB(bf0n, b ^ 1, 0);
                  asm volatile("s_waitcnt vmcnt(2)" ::: "memory"); }
    __builtin_amdgcn_s_barrier();
    MM(acc[0][1], af0, bf1);
  };

  // prologue: stage all 4 halves of tile 0, confirm h0,h1,h2, read tile 0's (af0,bf0)
  STAGE_HALF(0, 0, 0);
  STAGE_HALF(0, 0, 1);
  STAGE_HALF(0, 0, 2);
  STAGE_HALF(0, 0, 3);
  asm volatile("s_waitcnt vmcnt(2)" ::: "memory");
  __builtin_amdgcn_s_barrier();

  f16x8 afA[2][2], bfA[4][2], afB[2][2], bfB[4][2];
  LDA(afA, 0, 0);
  LDB(bfA, 0, 0);

  for (int tt = 0; tt < 24; tt += 2) {
    TILE(tt,     0, afA, bfA, afB, bfB);
    TILE(tt + 1, 1, afB, bfB, afA, bfA);
  }

  // ---- epilogue: dist + per-wave per-row argmin ----
  const int q    = lane >> 4;
  const int csub = lane & 15;

  float e2v[2][4];
  #pragma unroll
  for (int nq = 0; nq < 2; ++nq)
    #pragma unroll
    for (int n = 0; n < 4; ++n)
      e2v[nq][n] = e2[Cc + nq * 128 + qwc * 64 + n * 16 + csub];

  float bestv[16], besti[16];
  int rix = 0;
  #pragma unroll
  for (int mq = 0; mq < 2; ++mq)
    #pragma unroll
    for (int m = 0; m < 2; ++m)
      #pragma unroll
      for (int j = 0; j < 4; ++j, ++rix) {
        const int row = R + mq * 128 + qwr * 32 + m * 16 + q * 4 + j;
        const float xv = x2[row];
        float* drow = dist + (size_t)row * NCODE;
        float bv = -3.0e38f, bi = 0.0f;
        #pragma unroll
        for (int nq = 0; nq < 2; ++nq)
          #pragma unroll
          for (int n = 0; n < 4; ++n) {
            const int col = Cc + nq * 128 + qwc * 64 + n * 16 + csub;
            float xe = acc[mq][nq][m][n][j];
            float d2 = fmaxf((xv + e2v[nq][n]) - 2.0f * xe, 0.0f);
            float dv = -sqrtf(d2);
            drow[col] = dv;
            if (dv > bv) { bv = dv; bi = (float)col; }     // cols ascending => first-max kept
          }
        bestv[rix] = bv;
        besti[rix] = bi;
      }

  // reduce across the 16 lanes sharing each row
  #pragma unroll
  for (int msk = 1; msk < 16; msk <<= 1) {
    #pragma unroll
    for (int r = 0; r < 16; ++r) {
      float ov = __shfl_xor(bestv[r], msk);
      float oi = __shfl_xor(besti[r], msk);
      if (ov > bestv[r] || (ov == bestv[r] && oi < besti[r])) { bestv[r] = ov; besti[r] = oi; }
    }
  }
  if (csub == 0) {
    int rr = 0;
    #pragma unroll
    for (int mq = 0; mq < 2; ++mq)
      #pragma unroll
      for (int m = 0; m < 2; ++m)
        #pragma unroll
        for (int j = 0; j < 4; ++j, ++rr) {
          const int row = R + mq * 128 + qwr * 32 + m * 16 + q * 4 + j;
          part[(size_t)row * NPART + bn * 2 + qwc] = make_float2(bestv[rr], besti[rr]);
        }
  }
}

// ---------- final: per-row reduce of 64 partials, write index, gather code row ----------
__global__ __launch_bounds__(64)
void reduce_gather_kernel(const float2* __restrict__ part, const float* __restrict__ embed,
                          float* __restrict__ quant, float* __restrict__ ind)
{
  const int row = blockIdx.x;
  const int l = threadIdx.x;
  float2 a = part[(size_t)row * NPART + l];
  float bv = a.x, bi = a.y;
  #pragma unroll
  for (int m = 1; m < 64; m <<= 1) {
    float ov = __shfl_xor(bv, m);
    float oi = __shfl_xor(bi, m);
    if (ov > bv || (ov == bv && oi < bi)) { bv = ov; bi = oi; }
  }
  if (l == 0) ind[row] = bi;
  const int idx = (int)bi;
  const float4* src = reinterpret_cast<const float4*>(embed + (size_t)idx * DDIM);
  float4* dst = reinterpret_cast<float4*>(quant + (size_t)row * DDIM);
  dst[l]      = src[l];
  dst[l + 64] = src[l + 64];
}

extern "C" void kernel_launch(void* const* d_in, const int* in_sizes, int n_in,
                              void* d_out, int out_size, void* d_ws, size_t ws_size,
                              hipStream_t stream) {
  const float* x     = (const float*)d_in[0];
  const float* embed = (const float*)d_in[1];

  char* ws = (char*)d_ws;
  _Float16* xh = (_Float16*)(ws + WS_XH);
  _Float16* xl = (_Float16*)(ws + WS_XL);
  _Float16* eh = (_Float16*)(ws + WS_EH);
  _Float16* el = (_Float16*)(ws + WS_EL);
  float*    x2 = (float*)(ws + WS_X2);
  float*    e2 = (float*)(ws + WS_E2);
  float2*   part = (float2*)(ws + WS_PART);

  float* quant = (float*)d_out;
  float* ind   = (float*)d_out + OFF_IND;
  float* dist  = (float*)d_out + OFF_DIST;

  prep_kernel<<<dim3(NROWS + NCODE), 128, 0, stream>>>(x, embed, xh, xl, eh, el, x2, e2);
  dist_gemm_kernel<<<dim3(NBM * NBN), 512, 0, stream>>>(xh, xl, eh, el, x2, e2, dist, part);
  reduce_gather_kernel<<<dim3(NROWS), 64, 0, stream>>>(part, embed, quant, ind);
}

// Round 6
// 2092.741 us; speedup vs baseline: 1.4585x; 1.4585x over previous
//
#include <hip/hip_runtime.h>
#include <hip/hip_fp16.h>
#include <stdint.h>

typedef _Float16 f16x8 __attribute__((ext_vector_type(8)));
typedef _Float16 f16x4 __attribute__((ext_vector_type(4)));
typedef float    f32x4 __attribute__((ext_vector_type(4)));

static constexpr int NROWS = 32768;   // b*n
static constexpr int NCODE = 8192;
static constexpr int DDIM  = 512;
static constexpr int BM = 256, BN = 256, BK = 64;
static constexpr int NBM = NROWS / BM;    // 128
static constexpr int NBN = NCODE / BN;    // 32
static constexpr int NPART = NBN * 2;     // 64 partials per row

// out layout (floats): quantize [NROWS*DDIM] | embed_ind [NROWS] | dist [NROWS*NCODE]
static constexpr size_t OFF_IND  = (size_t)NROWS * DDIM;
static constexpr size_t OFF_DIST = OFF_IND + NROWS;

// ws layout (bytes)
static constexpr size_t WS_XH   = 0;
static constexpr size_t WS_XL   = WS_XH + (size_t)NROWS * DDIM * 2;
static constexpr size_t WS_EH   = WS_XL + (size_t)NROWS * DDIM * 2;
static constexpr size_t WS_EL   = WS_EH + (size_t)NCODE * DDIM * 2;
static constexpr size_t WS_X2   = WS_EL + (size_t)NCODE * DDIM * 2;
static constexpr size_t WS_E2   = WS_X2 + (size_t)NROWS * 4;
static constexpr size_t WS_PART = WS_E2 + (size_t)NCODE * 4;

__device__ inline void gload_lds16(const void* g, void* l) {
  __builtin_amdgcn_global_load_lds((const __attribute__((address_space(1))) void*)g,
                                   (__attribute__((address_space(3))) void*)l,
                                   16, 0, 0);
}

// ---------- prep: fp32 -> (f16 hi, f16 lo) split + fp64-accumulated norms ----------
__global__ __launch_bounds__(128)
void prep_kernel(const float* __restrict__ x, const float* __restrict__ e,
                 _Float16* __restrict__ xh, _Float16* __restrict__ xl,
                 _Float16* __restrict__ eh, _Float16* __restrict__ el,
                 float* __restrict__ x2, float* __restrict__ e2)
{
  int bid = blockIdx.x;
  const float* src; _Float16 *dh, *dl; float* nrm;
  if (bid < NROWS) {
    src = x + (size_t)bid * DDIM;
    dh = xh + (size_t)bid * DDIM;  dl = xl + (size_t)bid * DDIM;
    nrm = x2 + bid;
  } else {
    int r = bid - NROWS;
    src = e + (size_t)r * DDIM;
    dh = eh + (size_t)r * DDIM;    dl = el + (size_t)r * DDIM;
    nrm = e2 + r;
  }
  int t = threadIdx.x;
  float4 v = reinterpret_cast<const float4*>(src)[t];
  double s = (double)v.x*v.x + (double)v.y*v.y + (double)v.z*v.z + (double)v.w*v.w;
  f16x4 h, l;
  h.x = (_Float16)v.x; l.x = (_Float16)(v.x - (float)h.x);
  h.y = (_Float16)v.y; l.y = (_Float16)(v.y - (float)h.y);
  h.z = (_Float16)v.z; l.z = (_Float16)(v.z - (float)h.z);
  h.w = (_Float16)v.w; l.w = (_Float16)(v.w - (float)h.w);
  reinterpret_cast<f16x4*>(dh)[t] = h;
  reinterpret_cast<f16x4*>(dl)[t] = l;
  #pragma unroll
  for (int m = 1; m < 64; m <<= 1) s += __shfl_xor(s, m);
  __shared__ double sh[2];
  if ((t & 63) == 0) sh[t >> 6] = s;
  __syncthreads();
  if (t == 0) nrm[0] = (float)(sh[0] + sh[1]);
}

// sync helpers
#define BARx __builtin_amdgcn_s_barrier()
#define VMC(n)  asm volatile("s_waitcnt vmcnt(" #n ")" ::: "memory")
#define LGK(n)  do { asm volatile("s_waitcnt lgkmcnt(" #n ")" ::: "memory"); \
                     __builtin_amdgcn_sched_barrier(0); } while (0)

// 16-MFMA cluster, forced inline so array refs dissolve (r5 lesson: no scratch)
__device__ __forceinline__ void MMX(f32x4 (&ac)[2][4], const f16x8 (&af)[2][2],
                                    const f16x8 (&bf)[4][2]) {
  __builtin_amdgcn_s_setprio(1);
  #pragma unroll
  for (int m = 0; m < 2; ++m)
    #pragma unroll
    for (int n = 0; n < 4; ++n)
      #pragma unroll
      for (int ks = 0; ks < 2; ++ks)
        ac[m][n] = __builtin_amdgcn_mfma_f32_16x16x32_f16(af[m][ks], bf[n][ks], ac[m][n], 0, 0, 0);
  __builtin_amdgcn_s_setprio(0);
}

// ---------- main: 256x256 read-ahead pipelined split-GEMM + dist epilogue + partial argmin ----------
// Halves: h0=A rows0-127, h1=B rows0-127, h2=A rows128-255, h3=B rows128-255 (2 gloads/wave each).
// Stage lead: S(t.p1)=h1(t+1) S(t.p2)=h2(t+1) S(t.p3)=h3(t+1) S(t.p4)=h0(t+2); vmcnt(4) each phase
// confirms the half staged exactly 2 phases earlier, right at its read deadline. ds_reads are issued
// one phase ahead of their consuming MFMA (consume via counted lgkmcnt after the barrier).
__global__ __launch_bounds__(512, 1)
void dist_gemm_kernel(const _Float16* __restrict__ xh, const _Float16* __restrict__ xl,
                      const _Float16* __restrict__ eh, const _Float16* __restrict__ el,
                      const float* __restrict__ x2, const float* __restrict__ e2,
                      float* __restrict__ dist, float2* __restrict__ part)
{
  __shared__ _Float16 L[2][2][BM * BK];   // [buf][A=0/B=1][256*64] = 128 KiB

  const int tid  = threadIdx.x;
  const int wid  = tid >> 6;
  const int lane = tid & 63;
  const int qwr  = wid >> 1;      // 0..3 : 32-row band within each 128-row half
  const int qwc  = wid & 1;       // 0..1 : 64-col half within each 128-col half

  // Locality swizzle: each XCD owns a fixed 4-wide bn strip (2 MB B panel -> L2-resident).
  const int flat = blockIdx.x;
  const int xcd  = flat & 7;
  const int idx  = flat >> 3;          // 0..511
  const int bn   = xcd * 4 + (idx & 3);
  const int bm   = idx >> 2;           // 0..127
  const int R  = bm * BM;
  const int Cc = bn * BN;

  const int l3 = lane >> 3;
  const int l7 = lane & 7;
  const int srcslot = ((l7 ^ l3) << 4);   // pre-swizzled global 16B-slot (inverse of read swizzle)

  auto STAGE_HALF = [&](int t, int nb, int half) {
    const int ab = half & 1;
    const int hh = half >> 1;
    const _Float16* base;
    size_t rowbase;
    if (ab == 0) { base = (t < 16) ? xh : xl;              rowbase = (size_t)R;  }
    else         { base = (t < 8 || t >= 16) ? eh : el;    rowbase = (size_t)Cc; }
    const int k0b = (t & 7) * (BK * 2);
    #pragma unroll
    for (int i = 0; i < 2; ++i) {
      const int rr = hh * 128 + wid * 16 + i * 8;
      gload_lds16((const char*)base + (rowbase + rr + l3) * (DDIM * 2) + k0b + srcslot,
                  &L[nb][ab][rr * BK]);
    }
  };

  const int l15   = lane & 15;
  const int kslot = (lane >> 4) << 4;     // 0,16,32,48 byte k-slot

  auto LDA = [&](f16x8 (&af)[2][2], int b, int mq) {
    #pragma unroll
    for (int m = 0; m < 2; ++m)
      #pragma unroll
      for (int ks = 0; ks < 2; ++ks) {
        const int row = mq * 128 + qwr * 32 + m * 16 + l15;
        const int kb  = (ks * 64 + kslot) ^ ((row & 7) << 4);
        af[m][ks] = *(const f16x8*)((const char*)&L[b][0][0] + row * 128 + kb);
      }
  };
  auto LDB = [&](f16x8 (&bf)[4][2], int b, int nq) {
    #pragma unroll
    for (int n = 0; n < 4; ++n)
      #pragma unroll
      for (int ks = 0; ks < 2; ++ks) {
        const int row = nq * 128 + qwc * 64 + n * 16 + l15;
        const int kb  = (ks * 64 + kslot) ^ ((row & 7) << 4);
        bf[n][ks] = *(const f16x8*)((const char*)&L[b][1][0] + row * 128 + kb);
      }
  };

  f32x4 acc[2][2][2][4] = {};   // [mq][nq][m][n]

// One tile, guard-free (valid for T <= 21: stages T+1 and T+2).
// AF0/BF0 were ds_read at T-1.p4; AF0N/BF0N are read here at p4 for tile T+1.
#define TILE4(T, B, AF0, BF0, AF0N, BF0N)                                     \
  {                                                                           \
    f16x8 af1[2][2], bf1[4][2];                                               \
    /* p1: MM(0,0) */                                                         \
    LDA(af1, (B), 1);  STAGE_HALF((T) + 1, (B) ^ 1, 1);  VMC(4);  BARx;       \
    LGK(4);  MMX(acc[0][0], AF0, BF0);  BARx;                                 \
    /* p2: MM(1,0) */                                                         \
    LDB(bf1, (B), 1);  STAGE_HALF((T) + 1, (B) ^ 1, 2);  VMC(4);  BARx;       \
    LGK(8);  MMX(acc[1][0], af1, BF0);  BARx;                                 \
    /* p3: MM(1,1) */                                                         \
    STAGE_HALF((T) + 1, (B) ^ 1, 3);  VMC(4);  BARx;                          \
    LGK(0);  MMX(acc[1][1], af1, bf1);  BARx;                                 \
    /* p4: MM(0,1); read next tile's quadrant-0 frags */                      \
    LDA(AF0N, (B) ^ 1, 0);  LDB(BF0N, (B) ^ 1, 0);                            \
    STAGE_HALF((T) + 2, (B), 0);  VMC(4);  BARx;                              \
    MMX(acc[0][1], AF0, bf1);  BARx;                                          \
  }

  // prologue: h0..h3 of tile0 (buf0) + h0 of tile1 (buf1); confirm h0,h1,h2(0)
  STAGE_HALF(0, 0, 0);
  STAGE_HALF(0, 0, 1);
  STAGE_HALF(0, 0, 2);
  STAGE_HALF(0, 0, 3);
  STAGE_HALF(1, 1, 0);
  VMC(4);
  BARx;

  f16x8 afA[2][2], bfA[4][2], afB[2][2], bfB[4][2];
  LDA(afA, 0, 0);
  LDB(bfA, 0, 0);

  for (int tt = 0; tt < 22; tt += 2) {
    TILE4(tt,     0, afA, bfA, afB, bfB)
    TILE4(tt + 1, 1, afB, bfB, afA, bfA)
  }

  // ---- peeled tile 22 (buf0) ----
  {
    f16x8 af1[2][2], bf1[4][2];
    LDA(af1, 0, 1);  STAGE_HALF(23, 1, 1);  VMC(4);  BARx;
    LGK(4);  MMX(acc[0][0], afA, bfA);  BARx;
    LDB(bf1, 0, 1);  STAGE_HALF(23, 1, 2);  VMC(4);  BARx;
    LGK(8);  MMX(acc[1][0], af1, bfA);  BARx;
    STAGE_HALF(23, 1, 3);  VMC(4);  BARx;
    LGK(0);  MMX(acc[1][1], af1, bf1);  BARx;
    LDA(afB, 1, 0);  LDB(bfB, 1, 0);  VMC(2);  BARx;
    MMX(acc[0][1], afA, bf1);  BARx;
  }
  // ---- peeled tile 23 (buf1) ----
  {
    f16x8 af1[2][2], bf1[4][2];
    LDA(af1, 1, 1);  VMC(0);  BARx;
    LGK(4);  MMX(acc[0][0], afB, bfB);  BARx;
    LDB(bf1, 1, 1);  BARx;
    LGK(8);  MMX(acc[1][0], af1, bfB);  BARx;
    BARx;
    LGK(0);  MMX(acc[1][1], af1, bf1);  BARx;
    MMX(acc[0][1], afB, bf1);
  }

  // ---- epilogue: dist + per-wave per-row argmin ----
  const int q    = lane >> 4;
  const int csub = lane & 15;

  float e2v[2][4];
  #pragma unroll
  for (int nq = 0; nq < 2; ++nq)
    #pragma unroll
    for (int n = 0; n < 4; ++n)
      e2v[nq][n] = e2[Cc + nq * 128 + qwc * 64 + n * 16 + csub];

  float bestv[16], besti[16];
  int rix = 0;
  #pragma unroll
  for (int mq = 0; mq < 2; ++mq)
    #pragma unroll
    for (int m = 0; m < 2; ++m)
      #pragma unroll
      for (int j = 0; j < 4; ++j, ++rix) {
        const int row = R + mq * 128 + qwr * 32 + m * 16 + q * 4 + j;
        const float xv = x2[row];
        float* drow = dist + (size_t)row * NCODE;
        float bv = -3.0e38f, bi = 0.0f;
        #pragma unroll
        for (int nq = 0; nq < 2; ++nq)
          #pragma unroll
          for (int n = 0; n < 4; ++n) {
            const int col = Cc + nq * 128 + qwc * 64 + n * 16 + csub;
            float xe = acc[mq][nq][m][n][j];
            float d2 = fmaxf((xv + e2v[nq][n]) - 2.0f * xe, 0.0f);
            float dv = -sqrtf(d2);
            drow[col] = dv;
            if (dv > bv) { bv = dv; bi = (float)col; }     // cols ascending => first-max kept
          }
        bestv[rix] = bv;
        besti[rix] = bi;
      }

  // reduce across the 16 lanes sharing each row
  #pragma unroll
  for (int msk = 1; msk < 16; msk <<= 1) {
    #pragma unroll
    for (int r = 0; r < 16; ++r) {
      float ov = __shfl_xor(bestv[r], msk);
      float oi = __shfl_xor(besti[r], msk);
      if (ov > bestv[r] || (ov == bestv[r] && oi < besti[r])) { bestv[r] = ov; besti[r] = oi; }
    }
  }
  if (csub == 0) {
    int rr = 0;
    #pragma unroll
    for (int mq = 0; mq < 2; ++mq)
      #pragma unroll
      for (int m = 0; m < 2; ++m)
        #pragma unroll
        for (int j = 0; j < 4; ++j, ++rr) {
          const int row = R + mq * 128 + qwr * 32 + m * 16 + q * 4 + j;
          part[(size_t)row * NPART + bn * 2 + qwc] = make_float2(bestv[rr], besti[rr]);
        }
  }
}

// ---------- final: per-row reduce of 64 partials, write index, gather code row ----------
__global__ __launch_bounds__(64)
void reduce_gather_kernel(const float2* __restrict__ part, const float* __restrict__ embed,
                          float* __restrict__ quant, float* __restrict__ ind)
{
  const int row = blockIdx.x;
  const int l = threadIdx.x;
  float2 a = part[(size_t)row * NPART + l];
  float bv = a.x, bi = a.y;
  #pragma unroll
  for (int m = 1; m < 64; m <<= 1) {
    float ov = __shfl_xor(bv, m);
    float oi = __shfl_xor(bi, m);
    if (ov > bv || (ov == bv && oi < bi)) { bv = ov; bi = oi; }
  }
  if (l == 0) ind[row] = bi;
  const int idx = (int)bi;
  const float4* src = reinterpret_cast<const float4*>(embed + (size_t)idx * DDIM);
  float4* dst = reinterpret_cast<float4*>(quant + (size_t)row * DDIM);
  dst[l]      = src[l];
  dst[l + 64] = src[l + 64];
}

extern "C" void kernel_launch(void* const* d_in, const int* in_sizes, int n_in,
                              void* d_out, int out_size, void* d_ws, size_t ws_size,
                              hipStream_t stream) {
  const float* x     = (const float*)d_in[0];
  const float* embed = (const float*)d_in[1];

  char* ws = (char*)d_ws;
  _Float16* xh = (_Float16*)(ws + WS_XH);
  _Float16* xl = (_Float16*)(ws + WS_XL);
  _Float16* eh = (_Float16*)(ws + WS_EH);
  _Float16* el = (_Float16*)(ws + WS_EL);
  float*    x2 = (float*)(ws + WS_X2);
  float*    e2 = (float*)(ws + WS_E2);
  float2*   part = (float2*)(ws + WS_PART);

  float* quant = (float*)d_out;
  float* ind   = (float*)d_out + OFF_IND;
  float* dist  = (float*)d_out + OFF_DIST;

  prep_kernel<<<dim3(NROWS + NCODE), 128, 0, stream>>>(x, embed, xh, xl, eh, el, x2, e2);
  dist_gemm_kernel<<<dim3(NBM * NBN), 512, 0, stream>>>(xh, xl, eh, el, x2, e2, dist, part);
  reduce_gather_kernel<<<dim3(NROWS), 64, 0, stream>>>(part, embed, quant, ind);
}

// Round 7
// 945.511 us; speedup vs baseline: 3.2281x; 2.2133x over previous
//
#include <hip/hip_runtime.h>
#include <hip/hip_fp16.h>
#include <stdint.h>

typedef _Float16 f16x8 __attribute__((ext_vector_type(8)));
typedef _Float16 f16x4 __attribute__((ext_vector_type(4)));
typedef float    f32x4 __attribute__((ext_vector_type(4)));

static constexpr int NROWS = 32768;   // b*n
static constexpr int NCODE = 8192;
static constexpr int DDIM  = 512;
static constexpr int BM = 256, BN = 256, BK = 64;
static constexpr int NBM = NROWS / BM;    // 128
static constexpr int NBN = NCODE / BN;    // 32
static constexpr int NPART = NBN * 2;     // 64 partials per row

// out layout (floats): quantize [NROWS*DDIM] | embed_ind [NROWS] | dist [NROWS*NCODE]
static constexpr size_t OFF_IND  = (size_t)NROWS * DDIM;
static constexpr size_t OFF_DIST = OFF_IND + NROWS;

// ws layout (bytes)
static constexpr size_t WS_XH   = 0;
static constexpr size_t WS_XL   = WS_XH + (size_t)NROWS * DDIM * 2;
static constexpr size_t WS_EH   = WS_XL + (size_t)NROWS * DDIM * 2;
static constexpr size_t WS_EL   = WS_EH + (size_t)NCODE * DDIM * 2;
static constexpr size_t WS_X2   = WS_EL + (size_t)NCODE * DDIM * 2;
static constexpr size_t WS_E2   = WS_X2 + (size_t)NROWS * 4;
static constexpr size_t WS_PART = WS_E2 + (size_t)NCODE * 4;

__device__ inline void gload_lds16(const void* g, void* l) {
  __builtin_amdgcn_global_load_lds((const __attribute__((address_space(1))) void*)g,
                                   (__attribute__((address_space(3))) void*)l,
                                   16, 0, 0);
}

// ---------- prep: fp32 -> (f16 hi, f16 lo) split + fp64-accumulated norms ----------
__global__ __launch_bounds__(128)
void prep_kernel(const float* __restrict__ x, const float* __restrict__ e,
                 _Float16* __restrict__ xh, _Float16* __restrict__ xl,
                 _Float16* __restrict__ eh, _Float16* __restrict__ el,
                 float* __restrict__ x2, float* __restrict__ e2)
{
  int bid = blockIdx.x;
  const float* src; _Float16 *dh, *dl; float* nrm;
  if (bid < NROWS) {
    src = x + (size_t)bid * DDIM;
    dh = xh + (size_t)bid * DDIM;  dl = xl + (size_t)bid * DDIM;
    nrm = x2 + bid;
  } else {
    int r = bid - NROWS;
    src = e + (size_t)r * DDIM;
    dh = eh + (size_t)r * DDIM;    dl = el + (size_t)r * DDIM;
    nrm = e2 + r;
  }
  int t = threadIdx.x;
  float4 v = reinterpret_cast<const float4*>(src)[t];
  double s = (double)v.x*v.x + (double)v.y*v.y + (double)v.z*v.z + (double)v.w*v.w;
  f16x4 h, l;
  h.x = (_Float16)v.x; l.x = (_Float16)(v.x - (float)h.x);
  h.y = (_Float16)v.y; l.y = (_Float16)(v.y - (float)h.y);
  h.z = (_Float16)v.z; l.z = (_Float16)(v.z - (float)h.z);
  h.w = (_Float16)v.w; l.w = (_Float16)(v.w - (float)h.w);
  reinterpret_cast<f16x4*>(dh)[t] = h;
  reinterpret_cast<f16x4*>(dl)[t] = l;
  #pragma unroll
  for (int m = 1; m < 64; m <<= 1) s += __shfl_xor(s, m);
  __shared__ double sh[2];
  if ((t & 63) == 0) sh[t >> 6] = s;
  __syncthreads();
  if (t == 0) nrm[0] = (float)(sh[0] + sh[1]);
}

// sync helpers
#define BARx __builtin_amdgcn_s_barrier()
#define VMC(n)  asm volatile("s_waitcnt vmcnt(" #n ")" ::: "memory")

// 16-MFMA cluster, forced inline so array refs dissolve
__device__ __forceinline__ void MMX(f32x4 (&ac)[2][4], const f16x8 (&af)[2][2],
                                    const f16x8 (&bf)[4][2]) {
  __builtin_amdgcn_s_setprio(1);
  #pragma unroll
  for (int m = 0; m < 2; ++m)
    #pragma unroll
    for (int n = 0; n < 4; ++n)
      #pragma unroll
      for (int ks = 0; ks < 2; ++ks)
        ac[m][n] = __builtin_amdgcn_mfma_f32_16x16x32_f16(af[m][ks], bf[n][ks], ac[m][n], 0, 0, 0);
  __builtin_amdgcn_s_setprio(0);
}

// ---------- main: 256x256 4-phase/tile pipelined split-GEMM (m201-style) ----------
// Halves: h0=A rows0-127, h1=B rows0-127, h2=A rows128-255, h3=B rows128-255 (2 gloads/wave each).
// Stage stream: p1:h1(t+1) p2:h2(t+1) p3:h3(t+1) p4:h0(t+2).  vmcnt(6) at p1,p2,p4 (3 half-tiles
// in flight); none at p3.  Every ds_read targets data whose confirming vmcnt+barrier happened in
// an EARLIER phase; reads are consumed by the same phase's MFMA after the phase barrier.
// One barrier per phase (WAR-safe: p4's h0(t+2) overwrite of buf b is 3 barriers after af0 reads).
__global__ __launch_bounds__(512, 1)
void dist_gemm_kernel(const _Float16* __restrict__ xh, const _Float16* __restrict__ xl,
                      const _Float16* __restrict__ eh, const _Float16* __restrict__ el,
                      const float* __restrict__ x2, const float* __restrict__ e2,
                      float* __restrict__ dist, float2* __restrict__ part)
{
  __shared__ _Float16 L[2][2][BM * BK];   // [buf][A=0/B=1][256*64] = 128 KiB

  const int tid  = threadIdx.x;
  const int wid  = tid >> 6;
  const int lane = tid & 63;
  const int qwr  = wid >> 1;      // 0..3 : 32-row band within each 128-row half
  const int qwc  = wid & 1;       // 0..1 : 64-col half within each 128-col half

  // Locality swizzle: each XCD owns a fixed 4-wide bn strip (2 MB B panel -> L2-resident).
  const int flat = blockIdx.x;
  const int xcd  = flat & 7;
  const int idx  = flat >> 3;          // 0..511
  const int bn   = xcd * 4 + (idx & 3);
  const int bm   = idx >> 2;           // 0..127
  const int R  = bm * BM;
  const int Cc = bn * BN;

  const int l3 = lane >> 3;
  const int l7 = lane & 7;
  const int srcslot = ((l7 ^ l3) << 4);   // pre-swizzled global 16B-slot (inverse of read swizzle)

  auto STAGE_HALF = [&](int t, int nb, int half) {
    const int ab = half & 1;
    const int hh = half >> 1;
    const _Float16* base;
    size_t rowbase;
    if (ab == 0) { base = (t < 16) ? xh : xl;              rowbase = (size_t)R;  }
    else         { base = (t < 8 || t >= 16) ? eh : el;    rowbase = (size_t)Cc; }
    const int k0b = (t & 7) * (BK * 2);
    #pragma unroll
    for (int i = 0; i < 2; ++i) {
      const int rr = hh * 128 + wid * 16 + i * 8;
      gload_lds16((const char*)base + (rowbase + rr + l3) * (DDIM * 2) + k0b + srcslot,
                  &L[nb][ab][rr * BK]);
    }
  };

  const int l15   = lane & 15;
  const int kslot = (lane >> 4) << 4;     // 0,16,32,48 byte k-slot

  auto LDA = [&](f16x8 (&af)[2][2], int b, int mq) {
    #pragma unroll
    for (int m = 0; m < 2; ++m)
      #pragma unroll
      for (int ks = 0; ks < 2; ++ks) {
        const int row = mq * 128 + qwr * 32 + m * 16 + l15;
        const int kb  = (ks * 64 + kslot) ^ ((row & 7) << 4);
        af[m][ks] = *(const f16x8*)((const char*)&L[b][0][0] + row * 128 + kb);
      }
  };
  auto LDB = [&](f16x8 (&bf)[4][2], int b, int nq) {
    #pragma unroll
    for (int n = 0; n < 4; ++n)
      #pragma unroll
      for (int ks = 0; ks < 2; ++ks) {
        const int row = nq * 128 + qwc * 64 + n * 16 + l15;
        const int kb  = (ks * 64 + kslot) ^ ((row & 7) << 4);
        bf[n][ks] = *(const f16x8*)((const char*)&L[b][1][0] + row * 128 + kb);
      }
  };

  f32x4 acc[2][2][2][4] = {};   // [mq][nq][m][n] = 128 accumulator regs

  // prologue: h0..h3 of tile0 (buf0) + h0 of tile1 (buf1) = 10 vmem ops;
  // vmcnt(6) confirms h0(0),h1(0) for the first p1 reads.
  STAGE_HALF(0, 0, 0);
  STAGE_HALF(0, 0, 1);
  STAGE_HALF(0, 0, 2);
  STAGE_HALF(0, 0, 3);
  STAGE_HALF(1, 1, 0);
  VMC(6);
  BARx;

  for (int t = 0; t < 22; ++t) {
    const int b = t & 1;
    f16x8 af0[2][2], af1[2][2], bf0[4][2], bf1[4][2];

    // p1: MM(0,0).  reads h0(t),h1(t) [confirmed p4(t-1) / prologue]
    LDA(af0, b, 0);  LDB(bf0, b, 0);
    STAGE_HALF(t + 1, b ^ 1, 1);
    VMC(6);  BARx;                      // confirms h2(t)
    MMX(acc[0][0], af0, bf0);

    // p2: MM(1,0).  reads h2(t) [confirmed p1]
    LDA(af1, b, 1);
    STAGE_HALF(t + 1, b ^ 1, 2);
    VMC(6);  BARx;                      // confirms h3(t)
    MMX(acc[1][0], af1, bf0);

    // p3: MM(1,1).  reads h3(t) [confirmed p2]
    LDB(bf1, b, 1);
    STAGE_HALF(t + 1, b ^ 1, 3);
    BARx;
    MMX(acc[1][1], af1, bf1);

    // p4: MM(0,1).  no reads; stage h0(t+2) into current buf (region done 3 barriers ago)
    STAGE_HALF(t + 2, b, 0);
    VMC(6);  BARx;                      // confirms h0(t+1),h1(t+1)
    MMX(acc[0][1], af0, bf1);
  }

  // ---- peeled tile 22 (buf0): stages only h1..h3(23) ----
  {
    f16x8 af0[2][2], af1[2][2], bf0[4][2], bf1[4][2];
    LDA(af0, 0, 0);  LDB(bf0, 0, 0);
    STAGE_HALF(23, 1, 1);
    VMC(6);  BARx;
    MMX(acc[0][0], af0, bf0);
    LDA(af1, 0, 1);
    STAGE_HALF(23, 1, 2);
    VMC(6);  BARx;
    MMX(acc[1][0], af1, bf0);
    LDB(bf1, 0, 1);
    STAGE_HALF(23, 1, 3);
    BARx;
    MMX(acc[1][1], af1, bf1);
    VMC(4);  BARx;                      // confirms h0(23),h1(23)
    MMX(acc[0][1], af0, bf1);
  }
  // ---- peeled tile 23 (buf1): drain ----
  {
    f16x8 af0[2][2], af1[2][2], bf0[4][2], bf1[4][2];
    LDA(af0, 1, 0);  LDB(bf0, 1, 0);
    VMC(2);  BARx;                      // confirms h2(23)
    MMX(acc[0][0], af0, bf0);
    LDA(af1, 1, 1);
    VMC(0);  BARx;                      // confirms h3(23)
    MMX(acc[1][0], af1, bf0);
    LDB(bf1, 1, 1);
    BARx;
    MMX(acc[1][1], af1, bf1);
    MMX(acc[0][1], af0, bf1);
  }

  // ---- epilogue: dist + per-wave per-row argmin ----
  const int q    = lane >> 4;
  const int csub = lane & 15;

  float e2v[2][4];
  #pragma unroll
  for (int nq = 0; nq < 2; ++nq)
    #pragma unroll
    for (int n = 0; n < 4; ++n)
      e2v[nq][n] = e2[Cc + nq * 128 + qwc * 64 + n * 16 + csub];

  float bestv[16], besti[16];
  int rix = 0;
  #pragma unroll
  for (int mq = 0; mq < 2; ++mq)
    #pragma unroll
    for (int m = 0; m < 2; ++m)
      #pragma unroll
      for (int j = 0; j < 4; ++j, ++rix) {
        const int row = R + mq * 128 + qwr * 32 + m * 16 + q * 4 + j;
        const float xv = x2[row];
        float* drow = dist + (size_t)row * NCODE;
        float bv = -3.0e38f, bi = 0.0f;
        #pragma unroll
        for (int nq = 0; nq < 2; ++nq)
          #pragma unroll
          for (int n = 0; n < 4; ++n) {
            const int col = Cc + nq * 128 + qwc * 64 + n * 16 + csub;
            float xe = acc[mq][nq][m][n][j];
            float d2 = fmaxf((xv + e2v[nq][n]) - 2.0f * xe, 0.0f);
            float dv = -sqrtf(d2);
            drow[col] = dv;
            if (dv > bv) { bv = dv; bi = (float)col; }     // cols ascending => first-max kept
          }
        bestv[rix] = bv;
        besti[rix] = bi;
      }

  // reduce across the 16 lanes sharing each row
  #pragma unroll
  for (int msk = 1; msk < 16; msk <<= 1) {
    #pragma unroll
    for (int r = 0; r < 16; ++r) {
      float ov = __shfl_xor(bestv[r], msk);
      float oi = __shfl_xor(besti[r], msk);
      if (ov > bestv[r] || (ov == bestv[r] && oi < besti[r])) { bestv[r] = ov; besti[r] = oi; }
    }
  }
  if (csub == 0) {
    int rr = 0;
    #pragma unroll
    for (int mq = 0; mq < 2; ++mq)
      #pragma unroll
      for (int m = 0; m < 2; ++m)
        #pragma unroll
        for (int j = 0; j < 4; ++j, ++rr) {
          const int row = R + mq * 128 + qwr * 32 + m * 16 + q * 4 + j;
          part[(size_t)row * NPART + bn * 2 + qwc] = make_float2(bestv[rr], besti[rr]);
        }
  }
}

// ---------- final: per-row reduce of 64 partials, write index, gather code row ----------
__global__ __launch_bounds__(64)
void reduce_gather_kernel(const float2* __restrict__ part, const float* __restrict__ embed,
                          float* __restrict__ quant, float* __restrict__ ind)
{
  const int row = blockIdx.x;
  const int l = threadIdx.x;
  float2 a = part[(size_t)row * NPART + l];
  float bv = a.x, bi = a.y;
  #pragma unroll
  for (int m = 1; m < 64; m <<= 1) {
    float ov = __shfl_xor(bv, m);
    float oi = __shfl_xor(bi, m);
    if (ov > bv || (ov == bv && oi < bi)) { bv = ov; bi = oi; }
  }
  if (l == 0) ind[row] = bi;
  const int idx = (int)bi;
  const float4* src = reinterpret_cast<const float4*>(embed + (size_t)idx * DDIM);
  float4* dst = reinterpret_cast<float4*>(quant + (size_t)row * DDIM);
  dst[l]      = src[l];
  dst[l + 64] = src[l + 64];
}

extern "C" void kernel_launch(void* const* d_in, const int* in_sizes, int n_in,
                              void* d_out, int out_size, void* d_ws, size_t ws_size,
                              hipStream_t stream) {
  const float* x     = (const float*)d_in[0];
  const float* embed = (const float*)d_in[1];

  char* ws = (char*)d_ws;
  _Float16* xh = (_Float16*)(ws + WS_XH);
  _Float16* xl = (_Float16*)(ws + WS_XL);
  _Float16* eh = (_Float16*)(ws + WS_EH);
  _Float16* el = (_Float16*)(ws + WS_EL);
  float*    x2 = (float*)(ws + WS_X2);
  float*    e2 = (float*)(ws + WS_E2);
  float2*   part = (float2*)(ws + WS_PART);

  float* quant = (float*)d_out;
  float* ind   = (float*)d_out + OFF_IND;
  float* dist  = (float*)d_out + OFF_DIST;

  prep_kernel<<<dim3(NROWS + NCODE), 128, 0, stream>>>(x, embed, xh, xl, eh, el, x2, e2);
  dist_gemm_kernel<<<dim3(NBM * NBN), 512, 0, stream>>>(xh, xl, eh, el, x2, e2, dist, part);
  reduce_gather_kernel<<<dim3(NROWS), 64, 0, stream>>>(part, embed, quant, ind);
}